// Round 7
// baseline (136.695 us; speedup 1.0000x reference)
//
#include <hip/hip_runtime.h>
#include <hip/hip_bf16.h>

// ---------- problem sizes (fixed by setup_inputs) ----------
#define BB 8
#define SS 4096
#define NN 256      // d_state = d_input = d_output
#define MM (BB*SS)  // 32768 rows
#define CHUNK 32
#define NCH (SS/CHUNK)  // 128 chunks per batch

// ---------- ws layout (bytes) ----------
#define WS_FINR_B  ((size_t)0)            // 1024 chunks x 256 n fp32 = 1 MB
#define WS_FINI_B  ((size_t)1 << 20)
#define WS_CP_B    ((size_t)2 << 20)      // Cpack 256 KB
#define WS_V_B     ((size_t)3 << 20)      // V bf16, 16 MB

typedef __bf16 bf16_t;
typedef bf16_t bf16x8 __attribute__((ext_vector_type(8)));
typedef float  f32x4  __attribute__((ext_vector_type(4)));
typedef unsigned int u32x4 __attribute__((ext_vector_type(4)));

__device__ inline bf16_t f2b(float f) {
    __hip_bfloat16 h = __float2bfloat16(f);
    return __builtin_bit_cast(bf16_t, h);
}
__device__ inline float b2f(bf16_t v) {
    unsigned u = (unsigned)__builtin_bit_cast(unsigned short, v) << 16;
    return __builtin_bit_cast(float, u);
}
__device__ inline bf16x8 cvt8(f32x4 a, f32x4 b) {
    bf16x8 o;
    o[0]=f2b(a[0]); o[1]=f2b(a[1]); o[2]=f2b(a[2]); o[3]=f2b(a[3]);
    o[4]=f2b(b[0]); o[5]=f2b(b[1]); o[6]=f2b(b[2]); o[7]=f2b(b[3]);
    return o;
}

// bilinear-discretization constants for state n
__device__ inline void ssm_consts(const float* llr, const float* li, const float* ldt,
                                  int n, float& Ar, float& Ai, float& sr, float& si) {
    float lr = -expf(llr[n]);
    float im = li[n];
    float dt = expf(ldt[n]);
    dt = fminf(fmaxf(dt, 0.005f), 0.1f);
    float hr = 0.5f * dt * lr, hi = 0.5f * dt * im;
    float dr = 1.f - hr, di = -hi;
    float inv = 1.f / (dr*dr + di*di);
    Ar = ((1.f + hr)*dr + hi*di) * inv;
    Ai = (hi*dr - (1.f + hr)*di) * inv;
    sr = dt * dr * inv;
    si = -dt * di * inv;
}

// swizzled 16B slot for (row, oct): octp = oct ^ (row&31)
__device__ inline int swz(int row, int oct) {
    return ((row*32 + (oct ^ (row & 31))) << 4);
}

// ============================================================
// kA (blocks 0..511): GEMM1 for 64 rows x 256 states (K=256, BK=64)
//   -> V to swizzled LDS -> vectorized V store + chunk-local finals.
// Blocks 512..527: pack [Cr | -Ci] into MFMA B-fragment order.
// Frag maps (verified m89/m91): A[m=lane&15][k=q*8+j], B[n=lane&15][k=q*8+j];
// C/D: col=lane&15, row=q*4+reg.
// ============================================================
__global__ __launch_bounds__(512, 4) void kA(
        const float* __restrict__ X,   const float* __restrict__ Bw,
        const float* __restrict__ llr, const float* __restrict__ li,
        const float* __restrict__ ldt, const float* __restrict__ Cr,
        const float* __restrict__ Ci,  __hip_bfloat16* __restrict__ V,
        float* __restrict__ finr,      float* __restrict__ fini,
        u32x4* __restrict__ Cpack) {
    __shared__ __align__(16) char smem[40960];
    bf16x8* ldsA = (bf16x8*)smem;              // 512 slots (8 KB)   [K-loop only]
    bf16x8* ldsB = (bf16x8*)(smem + 8192);     // 2048 slots (32 KB) [K-loop only]
    // V-swizzle region [0, 32K) used after the K-loop.

    int t = threadIdx.x;
    int bid = blockIdx.x;
    int w = t >> 6, lane = t & 63, q = lane >> 4, r = lane & 15;

    if (bid >= 512) {   // ---- Cpack ----
        int ks = bid - 512;                  // 0..15 virtual k-step
        const float* src = (ks < 8) ? Cr : Ci;
        float sign = (ks < 8) ? 1.f : -1.f;
        #pragma unroll
        for (int jj = 0; jj < 2; ++jj) {
            int s = t + 512 * jj;            // 1024 slots: ot*64+lane
            int ot = s >> 6, ln = s & 63;
            int o  = ot*16 + (ln & 15);
            int kb = (ks & 7)*32 + (ln >> 4)*8;
            bf16x8 v;
            #pragma unroll
            for (int e = 0; e < 8; ++e) v[e] = f2b(sign * src[o*256 + kb + e]);
            Cpack[(ks*16 + ot)*64 + ln] = __builtin_bit_cast(u32x4, v);
        }
        return;
    }

    int m0 = bid * 64;
    // ---------------- GEMM1 ----------------
    int mt2 = (w & 1) * 2;          // wave's 2 m-subtiles (of 4)
    int nt4 = (w >> 1) * 4;         // wave's 4 n-subtiles (of 16)
    f32x4 acc1[2][4] = {};
    for (int kk = 0; kk < 4; ++kk) {
        int k0 = kk * 64;
        #pragma unroll
        for (int j = 0; j < 5; ++j) {          // 2560 slots / 512 thr
            int s = t + 512 * j;
            if (s < 512) {                     // A slot: tile = mt*2+kb
                int tile = s >> 6, ls = s & 63;
                int mt = tile >> 1, kb = tile & 1;
                int col = k0 + kb*32 + (ls >> 4)*8;
                const f32x4* p = (const f32x4*)(X + (size_t)(m0 + mt*16 + (ls & 15)) * 256 + col);
                ldsA[s] = cvt8(p[0], p[1]);
            } else {                           // B slot: tile = nt*2+kb
                int s2 = s - 512;
                int tile = s2 >> 6, ls = s2 & 63;
                int nt = tile >> 1, kb = tile & 1;
                int col = k0 + kb*32 + (ls >> 4)*8;
                const f32x4* p = (const f32x4*)(Bw + (size_t)(nt*16 + (ls & 15)) * 256 + col);
                ldsB[s2] = cvt8(p[0], p[1]);
            }
        }
        __syncthreads();
        #pragma unroll
        for (int kb = 0; kb < 2; ++kb) {
            bf16x8 af[2], bf_[4];
            #pragma unroll
            for (int i = 0; i < 2; ++i) af[i]  = ldsA[((mt2 + i)*2 + kb)*64 + lane];
            #pragma unroll
            for (int i = 0; i < 4; ++i) bf_[i] = ldsB[((nt4 + i)*2 + kb)*64 + lane];
            #pragma unroll
            for (int mi = 0; mi < 2; ++mi)
                #pragma unroll
                for (int ni = 0; ni < 4; ++ni)
                    acc1[mi][ni] = __builtin_amdgcn_mfma_f32_16x16x32_bf16(
                        af[mi], bf_[ni], acc1[mi][ni], 0, 0, 0);
        }
        __syncthreads();
    }
    // epilogue: V -> swizzled LDS [0,32K)
    #pragma unroll
    for (int mi = 0; mi < 2; ++mi)
        #pragma unroll
        for (int ni = 0; ni < 4; ++ni)
            #pragma unroll
            for (int reg = 0; reg < 4; ++reg) {
                int m = (mt2 + mi)*16 + q*4 + reg;
                int n = (nt4 + ni)*16 + r;
                *(bf16_t*)(smem + swz(m, n >> 3) + (n & 7)*2) =
                    f2b(acc1[mi][ni][reg]);
            }
    __syncthreads();

    // vectorized V store (LDS swizzled -> global row-major)
    #pragma unroll
    for (int j = 0; j < 4; ++j) {
        int s = t + 512*j;                     // 2048 slots: (row, oct)
        int row = s >> 5, oct = s & 31;
        *(u32x4*)(V + (size_t)(m0 + row) * NN + oct*8) =
            *(const u32x4*)(smem + swz(row, oct));
    }
    // chunk-local scan -> finals (fp32)
    {
        int n_s = t & 255, d_s = t >> 8;       // 256 states x 2 chunks
        int b = bid >> 6, cbase = (bid & 63) * 2;
        float Ar, Ai, sr, si;
        ssm_consts(llr, li, ldt, n_s, Ar, Ai, sr, si);
        int oct = n_s >> 3, j2 = (n_s & 7) * 2;
        float hr = 0.f, hi = 0.f;
        #pragma unroll 8
        for (int i = 0; i < CHUNK; ++i) {
            float v = b2f(*(const bf16_t*)(smem + swz(d_s*32 + i, oct) + j2));
            float tr = fmaf(Ar, hr, fmaf(-Ai, hi, sr * v));
            float ti = fmaf(Ar, hi, fmaf( Ai, hr, si * v));
            hr = tr; hi = ti;
        }
        int f = (b * NCH + cbase + d_s) * NN + n_s;
        finr[f] = hr; fini[f] = hi;
    }
}

// ============================================================
// kB: V global->swizzled LDS -> carry prefix (registers, L2 reads)
//     -> re-scan with carry init (in-place) -> GEMM2 (virtual K=512) -> out.
// 512 blocks x 512 threads, 64 KB LDS -> 2 blocks/CU.
// ============================================================
__global__ __launch_bounds__(512, 4) void kB(
        const __hip_bfloat16* __restrict__ V,
        const float* __restrict__ finr, const float* __restrict__ fini,
        const float* __restrict__ llr,  const float* __restrict__ li,
        const float* __restrict__ ldt,  const u32x4* __restrict__ Cpack,
        float* __restrict__ out) {
    __shared__ __align__(16) char smem[65536];   // hr/V @[0,32K), hi @[32K,64K)
    int t = threadIdx.x;
    int bid = blockIdx.x;
    int m0 = bid * 64;
    int b = bid >> 6, cbase = (bid & 63) * 2;

    // V -> swizzled LDS (b128 both sides)
    #pragma unroll
    for (int j = 0; j < 4; ++j) {
        int s = t + 512*j;
        int row = s >> 5, oct = s & 31;
        *(u32x4*)(smem + swz(row, oct)) =
            *(const u32x4*)(V + (size_t)(m0 + row) * NN + oct*8);
    }
    __syncthreads();

    {   // carry prefix + fused re-scan
        int n_s = t & 255, d_s = t >> 8;
        float Ar, Ai, sr, si;
        ssm_consts(llr, li, ldt, n_s, Ar, Ai, sr, si);
        float Pr = Ar, Pi = Ai;                // P = A^32
        #pragma unroll
        for (int i = 0; i < 5; ++i) { float tt = Pr*Pr - Pi*Pi; Pi = 2.f*Pr*Pi; Pr = tt; }
        float cr = 0.f, ci = 0.f;
        int ce = cbase + d_s;
        #pragma unroll 4
        for (int j = 0; j < ce; ++j) {
            int f = (b * NCH + j) * NN + n_s;
            float fr = finr[f], fi = fini[f];
            float tr = fmaf(Pr, cr, fmaf(-Pi, ci, fr));
            float ti = fmaf(Pr, ci, fmaf( Pi, cr, fi));
            cr = tr; ci = ti;
        }
        int oct = n_s >> 3, j2 = (n_s & 7) * 2;
        float hr = cr, hi = ci;                // carry as initial state (fp32 exact)
        #pragma unroll 8
        for (int i = 0; i < CHUNK; ++i) {
            int off = swz(d_s*32 + i, oct) + j2;
            float v = b2f(*(const bf16_t*)(smem + off));
            float tr = fmaf(Ar, hr, fmaf(-Ai, hi, sr * v));
            float ti = fmaf(Ar, hi, fmaf( Ai, hr, si * v));
            hr = tr; hi = ti;
            *(bf16_t*)(smem + off)         = f2b(hr);   // hr over V
            *(bf16_t*)(smem + 32768 + off) = f2b(hi);   // hi
        }
    }
    __syncthreads();

    // GEMM2: out[64x256] = [hr|hi] @ Cpack^T  (virtual K=512)
    int w = t >> 6, lane = t & 63, q = lane >> 4, r = lane & 15;
    f32x4 acc2[4][2] = {};
    #pragma unroll
    for (int ks = 0; ks < 16; ++ks) {
        int base = (ks < 8) ? 0 : 32768;
        int kin  = ks & 7;
        bf16x8 af[4];
        #pragma unroll
        for (int mt = 0; mt < 4; ++mt) {
            int ml = mt*16 + r;
            int octp = (kin*4 + q) ^ (ml & 31);
            af[mt] = *(const bf16x8*)(smem + base + ((ml*32 + octp) << 4));
        }
        #pragma unroll
        for (int u = 0; u < 2; ++u) {
            bf16x8 bf_ = __builtin_bit_cast(bf16x8, Cpack[(ks*16 + w*2 + u)*64 + lane]);
            #pragma unroll
            for (int mt = 0; mt < 4; ++mt)
                acc2[mt][u] = __builtin_amdgcn_mfma_f32_16x16x32_bf16(
                    af[mt], bf_, acc2[mt][u], 0, 0, 0);
        }
    }
    #pragma unroll
    for (int mt = 0; mt < 4; ++mt)
        #pragma unroll
        for (int u = 0; u < 2; ++u)
            #pragma unroll
            for (int reg = 0; reg < 4; ++reg)
                out[(size_t)(m0 + mt*16 + q*4 + reg) * NN + (w*2 + u)*16 + r] =
                    acc2[mt][u][reg];
}

extern "C" void kernel_launch(void* const* d_in, const int* in_sizes, int n_in,
                              void* d_out, int out_size, void* d_ws, size_t ws_size,
                              hipStream_t stream) {
    const float* x   = (const float*)d_in[0];
    const float* llr = (const float*)d_in[1];
    const float* li  = (const float*)d_in[2];
    const float* ldt = (const float*)d_in[3];
    const float* Bw  = (const float*)d_in[4];
    const float* Cr  = (const float*)d_in[5];
    const float* Ci  = (const float*)d_in[6];

    char* wsb = (char*)d_ws;
    float* finr  = (float*)(wsb + WS_FINR_B);
    float* fini  = (float*)(wsb + WS_FINI_B);
    u32x4* Cpack = (u32x4*)(wsb + WS_CP_B);
    __hip_bfloat16* V = (__hip_bfloat16*)(wsb + WS_V_B);

    kA<<<528, 512, 0, stream>>>(x, Bw, llr, li, ldt, Cr, Ci, V, finr, fini, Cpack);
    kB<<<512, 512, 0, stream>>>(V, finr, fini, llr, li, ldt, Cpack, (float*)d_out);
}